// Round 4
// baseline (278.643 us; speedup 1.0000x reference)
//
#include <hip/hip_runtime.h>
#include <math.h>

#define NN 64
#define CC 160
#define LL 4096
#define DD 160
#define MM 6
#define NCHUNK 32   // chunks per image; each chunk = 128 tokens (2 tiles of 64)
#define NTILE 2

__device__ __forceinline__ float bf2f(unsigned short u) {
  union { unsigned int i; float f; } v; v.i = ((unsigned int)u) << 16; return v.f;
}
__device__ __forceinline__ unsigned short f2bf(float f) {
  union { float f; unsigned int i; } v; v.f = f;
  unsigned int r = v.i + 0x7fffu + ((v.i >> 16) & 1u);
  return (unsigned short)(r >> 16);
}

// ---------------- k_init: scal = (d^-0.5 / tau); Wkq1 = scal * Wk @ q1^T ----------------
__global__ __launch_bounds__(256) void k_init(
    const float* log_tau, const float* slots_init, const float* q_g, const float* q_b,
    const float* Wq, const float* Wk, float* Wkq1, float* scal) {
  __shared__ float ln[MM * DD];
  __shared__ float qv[MM * DD];
  __shared__ float mu_s[MM], rs_s[MM];
  int tid = threadIdx.x;
  float x = log_tau[0];
  float sp = (x > 20.f) ? x : log1pf(expf(x));
  float scv = (1.0f / sqrtf((float)DD)) / (sp + 0.5f);
  if (blockIdx.x == 0 && tid == 0) scal[0] = scv;
  if (tid < MM) {
    float s = 0.f, ss = 0.f;
    for (int i = 0; i < DD; i++) { float v = slots_init[tid * DD + i]; s += v; ss += v * v; }
    float mu = s / DD, var = ss / DD - mu * mu;
    mu_s[tid] = mu; rs_s[tid] = rsqrtf(var + 1e-5f);
  }
  __syncthreads();
  for (int o = tid; o < MM * DD; o += 256) {
    int m = o / DD, d = o % DD;
    ln[o] = (slots_init[o] - mu_s[m]) * rs_s[m] * q_g[d] + q_b[d];
  }
  __syncthreads();
  for (int o = tid; o < MM * DD; o += 256) {
    int m = o / DD, d = o % DD;
    float acc = 0.f;
#pragma unroll 8
    for (int i = 0; i < DD; i++) acc += ln[m * DD + i] * Wq[i * DD + d];
    qv[o] = acc;
  }
  __syncthreads();
  for (int o = tid; o < 60; o += 256) {
    int c = blockIdx.x * 10 + o / 6, m = o % 6;
    float acc = 0.f;
#pragma unroll 8
    for (int d = 0; d < DD; d++) acc += Wk[c * DD + d] * qv[m * DD + d];
    Wkq1[c * 6 + m] = scv * acc;
  }
}

// ---------------- k_init2: P1 = g .* Wkq1; ab = [alpha | beta] ----------------
__global__ __launch_bounds__(256) void k_init2(
    const float* Wkq1, const float* kv_g, const float* kv_b, float* P1, float* ab) {
  int tid = threadIdx.x;
  for (int o = tid; o < DD * 6; o += 256) {
    int c = o / 6;
    P1[o] = kv_g[c] * Wkq1[o];
  }
  __syncthreads();
  if (tid < 12) {
    int m = tid % 6;
    float s = 0.f;
    if (tid < 6) { for (int c = 0; c < DD; c++) s += P1[c * 6 + m]; }
    else         { for (int c = 0; c < DD; c++) s += kv_b[c] * Wkq1[c * 6 + m]; }
    ab[tid] = s;
  }
}

// ---------------- k_pass1: raw-x fused {LN stats + logits} -> softmax -> A-accum + xln cache ----------------
__global__ __launch_bounds__(256) void k_pass1(
    const float* feat, const float* kv_g, const float* kv_b,
    const float* P1, const float* ab,
    unsigned short* xcache, float* Apart, float* Spart) {
  int b = blockIdx.x;
  int n = b >> 5, ch = b & 31;
  int tid = threadIdx.x;
  int lane = tid & 63, g = tid >> 6;
  __shared__ __align__(16) unsigned short xln[64][168];   // 336B row stride
  __shared__ float part[4][64][9];                        // s, ss, lgr[6] (+pad)
  __shared__ float att[64][6];
  __shared__ float P_s[160][6];
  __shared__ float kvg_s[160], kvb_s[160];
  __shared__ float sred[64][6];

  for (int o = tid; o < DD * 6; o += 256) ((float*)P_s)[o] = P1[o];
  for (int o = tid; o < DD; o += 256) { kvg_s[o] = kv_g[o]; kvb_s[o] = kv_b[o]; }
  float alpha[6], beta[6];
#pragma unroll
  for (int m = 0; m < 6; m++) { alpha[m] = ab[m]; beta[m] = ab[6 + m]; }
  float Aacc[6] = {0, 0, 0, 0, 0, 0};
  float Sacc[6] = {0, 0, 0, 0, 0, 0};
  __syncthreads();

  for (int t4 = 0; t4 < NTILE; t4++) {
    int tok0 = ch * (64 * NTILE) + t4 * 64;
    // ---- phase 0: load 40 raw channels; stats + logits partials fused ----
    const float* fp = feat + ((size_t)(n * CC + g * 40)) * LL + tok0 + lane;
    float rv[40];
    float s = 0.f, ss = 0.f;
    float lgr[6] = {0, 0, 0, 0, 0, 0};
#pragma unroll
    for (int i = 0; i < 40; i++) {
      float x = fp[(size_t)i * LL];
      rv[i] = x; s += x; ss += x * x;
      const float* pr = &P_s[g * 40 + i][0];
#pragma unroll
      for (int m = 0; m < 6; m++) lgr[m] += x * pr[m];
    }
    part[g][lane][0] = s; part[g][lane][1] = ss;
#pragma unroll
    for (int m = 0; m < 6; m++) part[g][lane][2 + m] = lgr[m];
    __syncthreads();
    // ---- phase 1: all-wave redundant combine; softmax; pack xln ----
    float S = 0.f, SS = 0.f, L[6] = {0, 0, 0, 0, 0, 0};
#pragma unroll
    for (int gg = 0; gg < 4; gg++) {
      S += part[gg][lane][0]; SS += part[gg][lane][1];
#pragma unroll
      for (int m = 0; m < 6; m++) L[m] += part[gg][lane][2 + m];
    }
    float mu = S / CC, var = SS / CC - mu * mu;
    float rs = rsqrtf(var + 1e-5f);
    float lg[6];
#pragma unroll
    for (int m = 0; m < 6; m++) lg[m] = rs * L[m] - rs * mu * alpha[m] + beta[m];
    float mx = lg[0];
#pragma unroll
    for (int m = 1; m < 6; m++) mx = fmaxf(mx, lg[m]);
    float e[6], sum = 0.f;
#pragma unroll
    for (int m = 0; m < 6; m++) { e[m] = __expf(lg[m] - mx); sum += e[m]; }
    float inv = 1.0f / sum;
    if (tid < 64) {
#pragma unroll
      for (int m = 0; m < 6; m++) {
        float a = e[m] * inv;
        att[lane][m] = a;
        Sacc[m] += a;
      }
    }
    // pack this wave's 40 channels of token `lane` (LN applied, bf16)
#pragma unroll
    for (int q5 = 0; q5 < 5; q5++) {
      unsigned short pk[8];
#pragma unroll
      for (int j = 0; j < 8; j++) {
        int c = g * 40 + q5 * 8 + j;
        float v = (rv[q5 * 8 + j] - mu) * rs * kvg_s[c] + kvb_s[c];
        pk[j] = f2bf(v);
      }
      *(uint4*)&xln[lane][g * 40 + q5 * 8] = *(const uint4*)pk;
    }
    __syncthreads();
    // ---- phase 2: A-accum (tid<160) || xln -> xcache copy (tid>=160) ----
    if (tid < DD) {
#pragma unroll 4
      for (int t = 0; t < 64; t++) {
        float xv = bf2f(xln[t][tid]);
        float a0 = att[t][0], a1 = att[t][1], a2 = att[t][2];
        float a3 = att[t][3], a4 = att[t][4], a5 = att[t][5];
        Aacc[0] += a0 * xv; Aacc[1] += a1 * xv; Aacc[2] += a2 * xv;
        Aacc[3] += a3 * xv; Aacc[4] += a4 * xv; Aacc[5] += a5 * xv;
      }
    } else {
      unsigned short* dst = xcache + ((size_t)(n * LL + tok0)) * DD;
      for (int i = tid - 160; i < 64 * 20; i += 96) {
        int row = i / 20, c8 = i % 20;
        *(uint4*)(dst + (size_t)row * DD + c8 * 8) = *(const uint4*)&xln[row][c8 * 8];
      }
    }
    __syncthreads();
  }
  // ---- finals ----
  if (tid < DD) {
#pragma unroll
    for (int m = 0; m < 6; m++) Apart[((size_t)b * 6 + m) * DD + tid] = Aacc[m];
  }
  if (tid < 64) {
#pragma unroll
    for (int m = 0; m < 6; m++) sred[tid][m] = Sacc[m];
  }
  __syncthreads();
  if (tid < 6) {
    float s = 0.f;
    for (int t = 0; t < 64; t++) s += sred[t][tid];
    Spart[b * 6 + tid] = s;
  }
}

// ---------------- k_pass2: read xln cache; logits @ Wkq2[n]; softmax; A-accum; attn write ----------------
__global__ __launch_bounds__(256) void k_pass2(
    const unsigned short* xcache, const float* Wkq2,
    float* Apart, float* Spart, float* attn_out) {
  int b = blockIdx.x;
  int n = b >> 5, ch = b & 31;
  int tid = threadIdx.x;
  __shared__ __align__(16) unsigned short xln[64][168];
  __shared__ float wkq_s[160][6];
  __shared__ float att[64][6];
  __shared__ float sred[64][6];
  const float* wsrc = Wkq2 + (size_t)n * DD * 6;
  for (int o = tid; o < DD * 6; o += 256) ((float*)wkq_s)[o] = wsrc[o];
  float Aacc[6] = {0, 0, 0, 0, 0, 0};
  float Sacc[6] = {0, 0, 0, 0, 0, 0};
  __syncthreads();

  for (int t4 = 0; t4 < NTILE; t4++) {
    int tok0 = ch * (64 * NTILE) + t4 * 64;
    const unsigned short* src = xcache + ((size_t)(n * LL + tok0)) * DD;
    for (int i = tid; i < 64 * 20; i += 256) {
      int row = i / 20, c8 = i % 20;
      *(uint4*)&xln[row][c8 * 8] = *(const uint4*)(src + (size_t)row * DD + c8 * 8);
    }
    __syncthreads();
    if (tid < 128) {
      int tl = tid >> 1, hf = tid & 1;
      const unsigned short* xrow = &xln[tl][hf * 80];
      float lg[6] = {0, 0, 0, 0, 0, 0};
#pragma unroll
      for (int u = 0; u < 10; u++) {
        uint4 kv = *(const uint4*)(xrow + u * 8);
        const unsigned short* kp = (const unsigned short*)&kv;
#pragma unroll
        for (int j = 0; j < 8; j++) {
          float kf = bf2f(kp[j]);
          const float* wr = &wkq_s[hf * 80 + u * 8 + j][0];
#pragma unroll
          for (int m = 0; m < 6; m++) lg[m] += kf * wr[m];
        }
      }
#pragma unroll
      for (int m = 0; m < 6; m++) lg[m] += __shfl_xor(lg[m], 1);
      float mx = lg[0];
#pragma unroll
      for (int m = 1; m < 6; m++) mx = fmaxf(mx, lg[m]);
      float e[6], sum = 0.f;
#pragma unroll
      for (int m = 0; m < 6; m++) { e[m] = __expf(lg[m] - mx); sum += e[m]; }
      float inv = 1.0f / sum;
      if (hf == 0) {
#pragma unroll
        for (int m = 0; m < 6; m++) {
          float a = e[m] * inv;
          att[tl][m] = a;
          Sacc[m] += a;
          attn_out[((size_t)(n * MM + m)) * LL + tok0 + tl] = a;
        }
      }
    }
    __syncthreads();
    if (tid < DD) {
#pragma unroll 4
      for (int t = 0; t < 64; t++) {
        float xv = bf2f(xln[t][tid]);
        float a0 = att[t][0], a1 = att[t][1], a2 = att[t][2];
        float a3 = att[t][3], a4 = att[t][4], a5 = att[t][5];
        Aacc[0] += a0 * xv; Aacc[1] += a1 * xv; Aacc[2] += a2 * xv;
        Aacc[3] += a3 * xv; Aacc[4] += a4 * xv; Aacc[5] += a5 * xv;
      }
    }
    __syncthreads();
  }
  if (tid < DD) {
#pragma unroll
    for (int m = 0; m < 6; m++) Apart[((size_t)b * 6 + m) * DD + tid] = Aacc[m];
  }
  if (tid < 128 && (tid & 1) == 0) {
#pragma unroll
    for (int m = 0; m < 6; m++) sred[tid >> 1][m] = Sacc[m];
  }
  __syncthreads();
  if (tid < 6) {
    float s = 0.f;
    for (int t = 0; t < 64; t++) s += sred[t][tid];
    Spart[b * 6 + tid] = s;
  }
}

// ---------------- k_slot2: fused per-n slot update, 512 threads ----------------
template <bool FIRST, bool LAST>
__global__ __launch_bounds__(512) void k_slot2(
    const float* slots_init, const float* Apart, const float* Spart, const float* Wv,
    const float* out_g, const float* out_b,
    const float* W1, const float* b1, const float* W2, const float* b2,
    const float* q_g, const float* q_b, const float* Wq, const float* Wk, const float* scal,
    float* slotbuf, float* Wkq2, float* Sfin, float* out_slots) {
  int n = blockIdx.x;
  int tid = threadIdx.x;
  __shared__ float a_s[MM * DD];
  __shared__ float s1[MM * DD];
  __shared__ float h[MM * 320];
  __shared__ float Sv[MM], mu_s[MM], rs_s[MM];

  if (tid < MM) {
    float s = 0.f;
#pragma unroll
    for (int p = 0; p < NCHUNK; p++) s += Spart[(n * NCHUNK + p) * 6 + tid];
    float sc = fmaxf(s, 1e-6f);
    Sv[tid] = sc;
    if (LAST) Sfin[n * 6 + tid] = sc;
  }
  for (int o = tid; o < MM * DD; o += 512) {
    float s = 0.f;
#pragma unroll
    for (int p = 0; p < NCHUNK; p++) s += Apart[(size_t)n * (NCHUNK * MM * DD) + p * (MM * DD) + o];
    a_s[o] = s;
  }
  __syncthreads();
  for (int o = tid; o < MM * DD; o += 512) {
    int m = o / DD, d = o % DD;
    float u = 0.f;
#pragma unroll 8
    for (int c = 0; c < DD; c++) u += a_s[m * DD + c] * Wv[c * DD + d];
    float prev = FIRST ? slots_init[o] : slotbuf[(size_t)n * MM * DD + o];
    s1[o] = prev + u / Sv[m];
  }
  __syncthreads();
  if (tid < 384) {
    int m = tid >> 6, l = tid & 63;
    const float* row = &s1[m * DD];
    float x0 = row[l], x1 = row[l + 64], x2 = (l < 32 ? row[l + 128] : 0.f);
    float s = x0 + x1 + x2, ss = x0 * x0 + x1 * x1 + x2 * x2;
#pragma unroll
    for (int off = 32; off >= 1; off >>= 1) { s += __shfl_xor(s, off); ss += __shfl_xor(ss, off); }
    if (l == 0) {
      float mu = s / DD, var = ss / DD - mu * mu;
      mu_s[m] = mu; rs_s[m] = rsqrtf(var + 1e-5f);
    }
  }
  __syncthreads();
  for (int o = tid; o < MM * DD; o += 512) {
    int m = o / DD, d = o % DD;
    s1[o] = (s1[o] - mu_s[m]) * rs_s[m] * out_g[d] + out_b[d];
  }
  __syncthreads();
  for (int o = tid; o < MM * 320; o += 512) {
    int m = o / 320, j = o % 320;
    float acc = b1[j];
#pragma unroll 8
    for (int d = 0; d < DD; d++) acc += s1[m * DD + d] * W1[d * 320 + j];
    h[o] = 0.5f * acc * (1.0f + erff(acc * 0.70710678118f));
  }
  __syncthreads();
  for (int o = tid; o < MM * DD; o += 512) {
    int m = o / DD, d = o % DD;
    float acc = b2[d];
#pragma unroll 8
    for (int j = 0; j < 320; j++) acc += h[m * 320 + j] * W2[j * DD + d];
    float val = s1[o] + acc;
    a_s[o] = val;
    if (LAST) out_slots[(size_t)n * MM * DD + o] = val;
    else slotbuf[(size_t)n * MM * DD + o] = val;
  }
  if (!LAST) {
    __syncthreads();
    if (tid < 384) {
      int m = tid >> 6, l = tid & 63;
      const float* row = &a_s[m * DD];
      float x0 = row[l], x1 = row[l + 64], x2 = (l < 32 ? row[l + 128] : 0.f);
      float s = x0 + x1 + x2, ss = x0 * x0 + x1 * x1 + x2 * x2;
#pragma unroll
      for (int off = 32; off >= 1; off >>= 1) { s += __shfl_xor(s, off); ss += __shfl_xor(ss, off); }
      if (l == 0) {
        float mu = s / DD, var = ss / DD - mu * mu;
        mu_s[m] = mu; rs_s[m] = rsqrtf(var + 1e-5f);
      }
    }
    __syncthreads();
    for (int o = tid; o < MM * DD; o += 512) {
      int m = o / DD, d = o % DD;
      s1[o] = (a_s[o] - mu_s[m]) * rs_s[m] * q_g[d] + q_b[d];
    }
    __syncthreads();
    for (int o = tid; o < MM * DD; o += 512) {
      int m = o / DD, d = o % DD;
      float acc = 0.f;
#pragma unroll 8
      for (int i = 0; i < DD; i++) acc += s1[m * DD + i] * Wq[i * DD + d];
      h[o] = acc;
    }
    __syncthreads();
    if (tid < DD) {
      int c = tid;
      float acc[MM] = {0, 0, 0, 0, 0, 0};
#pragma unroll 4
      for (int d = 0; d < DD; d++) {
        float wk = Wk[c * DD + d];
#pragma unroll
        for (int m = 0; m < MM; m++) acc[m] += wk * h[m * DD + d];
      }
      float sc = scal[0];
#pragma unroll
      for (int m = 0; m < MM; m++) Wkq2[(size_t)n * DD * 6 + c * 6 + m] = sc * acc[m];
    }
  }
}

// ---------------- k_norm: attn_map = attn / Sfin ----------------
__global__ __launch_bounds__(256) void k_norm(float* attn, const float* Sfin) {
  int idx = blockIdx.x * 256 + threadIdx.x;
  size_t base = (size_t)idx * 4;
  int nm = (int)(base >> 12);
  float s = Sfin[nm];
  float4 v = *(float4*)(attn + base);
  float inv = 1.0f / s;
  v.x *= inv; v.y *= inv; v.z *= inv; v.w *= inv;
  *(float4*)(attn + base) = v;
}

extern "C" void kernel_launch(void* const* d_in, const int* in_sizes, int n_in,
                              void* d_out, int out_size, void* d_ws, size_t ws_size,
                              hipStream_t stream) {
  const float* feat       = (const float*)d_in[0];
  const float* slots_init = (const float*)d_in[1];
  const float* log_tau    = (const float*)d_in[2];
  const float* kv_g       = (const float*)d_in[3];
  const float* kv_b       = (const float*)d_in[4];
  const float* Wk         = (const float*)d_in[5];
  const float* Wv         = (const float*)d_in[6];
  const float* q_g        = (const float*)d_in[7];
  const float* q_b        = (const float*)d_in[8];
  const float* Wq         = (const float*)d_in[9];
  const float* out_g      = (const float*)d_in[10];
  const float* out_b      = (const float*)d_in[11];
  const float* W1         = (const float*)d_in[12];
  const float* b1         = (const float*)d_in[13];
  const float* W2         = (const float*)d_in[14];
  const float* b2         = (const float*)d_in[15];
  float* out = (float*)d_out;
  float* out_attn = out + NN * MM * DD;

  // workspace: xcache (84 MB) + fp32 partials
  unsigned short* xcache = (unsigned short*)d_ws;          // [64][4096][160] bf16
  float* Wkq1    = (float*)(xcache + (size_t)NN * LL * DD);// [160][6]
  float* Wkq2    = Wkq1 + DD * 6;                          // [64][160][6]
  float* P1      = Wkq2 + (size_t)NN * DD * 6;             // [160][6]
  float* ab      = P1 + DD * 6;                            // [12]
  float* Apart   = ab + 16;                                // [2048][6][160]
  float* Spart   = Apart + (size_t)NN * NCHUNK * MM * DD;  // [2048][6]
  float* Sfin    = Spart + (size_t)NN * NCHUNK * MM;       // [64][6]
  float* scal    = Sfin + NN * MM;                         // [1]
  float* slotbuf = scal + 8;                               // [64][6][160]
  size_t required = (size_t)((char*)(slotbuf + NN * MM * DD) - (char*)d_ws);
  if (ws_size < required) return;

  k_init<<<16, 256, 0, stream>>>(log_tau, slots_init, q_g, q_b, Wq, Wk, Wkq1, scal);
  k_init2<<<1, 256, 0, stream>>>(Wkq1, kv_g, kv_b, P1, ab);
  k_pass1<<<NN * NCHUNK, 256, 0, stream>>>(feat, kv_g, kv_b, P1, ab, xcache, Apart, Spart);
  k_slot2<true, false><<<NN, 512, 0, stream>>>(slots_init, Apart, Spart, Wv, out_g, out_b,
                                               W1, b1, W2, b2, q_g, q_b, Wq, Wk, scal,
                                               slotbuf, Wkq2, Sfin, out);
  k_pass2<<<NN * NCHUNK, 256, 0, stream>>>(xcache, Wkq2, Apart, Spart, out_attn);
  k_slot2<false, true><<<NN, 512, 0, stream>>>(slots_init, Apart, Spart, Wv, out_g, out_b,
                                               W1, b1, W2, b2, q_g, q_b, Wq, Wk, scal,
                                               slotbuf, Wkq2, Sfin, out);
  k_norm<<<(NN * MM * LL) / 1024, 256, 0, stream>>>(out_attn, Sfin);
}